// Round 3
// baseline (1151.943 us; speedup 1.0000x reference)
//
#include <hip/hip_runtime.h>
#include <hip/hip_fp16.h>
#include <math.h>

#define NN 30000
#define NE 480000
#define NBLK 1536     // 6 blocks/CU x 256 CU, co-resident (launch_bounds caps VGPR at 85)
#define NTHR 256
#define GSZ (NBLK * NTHR)   // 393216
#define NTILE 1875          // NN/16 node-tiles
#define NSUB 16             // barrier fan-in
#define SUBCNT (NBLK / NSUB)
#define INVSCALE (1.0f / 4096.0f)

// R16: R15's mega-kernel at 1 block/CU (8 waves) ran the latency-bound gather phases
// with 3x less TLP than the multi-dispatch layers (24 waves/CU) -> 604us. Keep the
// dispatch merge (gaps ~150-200us were real), restore occupancy: 1536x256 blocks,
// launch_bounds(256,6), two-level split-counter barrier, ticket work queue per layer.

typedef _Float16 half8 __attribute__((ext_vector_type(8)));
typedef float floatx4 __attribute__((ext_vector_type(4)));
typedef float floatx2 __attribute__((ext_vector_type(2)));

__device__ __forceinline__ float lrelu(float v) { return v > 0.0f ? v : v * 0.02f; }

__device__ __forceinline__ float4 fma4(float4 v, float w, float4 a) {
    a.x = fmaf(v.x, w, a.x);
    a.y = fmaf(v.y, w, a.y);
    a.z = fmaf(v.z, w, a.z);
    a.w = fmaf(v.w, w, a.w);
    return a;
}

__device__ __forceinline__ float4 loadh4(const __half* p) {
    uint2 raw = *(const uint2*)p;
    float2 f0 = __half22float2(*(__half2*)&raw.x);
    float2 f1 = __half22float2(*(__half2*)&raw.y);
    return make_float4(f0.x, f0.y, f1.x, f1.y);
}

__device__ __forceinline__ void cvtf8x8(uint2 raw, float4* lo, float4* hi) {
    floatx2 a = __builtin_amdgcn_cvt_pk_f32_fp8(raw.x, false);
    floatx2 b = __builtin_amdgcn_cvt_pk_f32_fp8(raw.x, true);
    floatx2 c = __builtin_amdgcn_cvt_pk_f32_fp8(raw.y, false);
    floatx2 d = __builtin_amdgcn_cvt_pk_f32_fp8(raw.y, true);
    *lo = make_float4(a.x, a.y, b.x, b.y);
    *hi = make_float4(c.x, c.y, d.x, d.y);
}

__device__ __forceinline__ void loadf8x8(const unsigned char* p, float4* lo, float4* hi) {
    cvtf8x8(*(const uint2*)p, lo, hi);
}

__device__ __forceinline__ void stnt_f8(unsigned char* p, float v) {
    int pk = __builtin_amdgcn_cvt_pk_fp8_f32(v, v, 0, false);  // RNE, saturates
    __builtin_nontemporal_store((unsigned char)pk, p);
}

// ---- two-level device-scope generation barrier ----
// bar layout (ints): [0..7] tickets | [16 + i*16] 16 sub-counters (64B apart)
//                    | [512] master | [528] generation
// 1536 same-line atomic arrivals would serialize (~8us); 16-way fan-in is ~1us.
// Release/acquire chain: block stores -> sub ACQ_REL -> master ACQ_REL -> gen RELEASE;
// spinners ACQUIRE gen on exit. Counter resets are ordered before the gen bump.
__device__ __forceinline__ void gbar(int* bar, int bid, int my_gen) {
    __syncthreads();
    if (threadIdx.x == 0) {
        int* gen = bar + 528;
        int sub = bid & (NSUB - 1);
        int prev = __hip_atomic_fetch_add(bar + 16 + sub * 16, 1, __ATOMIC_ACQ_REL,
                                          __HIP_MEMORY_SCOPE_AGENT);
        if (prev == SUBCNT - 1) {
            __hip_atomic_store(bar + 16 + sub * 16, 0, __ATOMIC_RELAXED,
                               __HIP_MEMORY_SCOPE_AGENT);
            int mprev = __hip_atomic_fetch_add(bar + 512, 1, __ATOMIC_ACQ_REL,
                                               __HIP_MEMORY_SCOPE_AGENT);
            if (mprev == NSUB - 1) {
                __hip_atomic_store(bar + 512, 0, __ATOMIC_RELAXED,
                                   __HIP_MEMORY_SCOPE_AGENT);
                __hip_atomic_fetch_add(gen, 1, __ATOMIC_RELEASE,
                                       __HIP_MEMORY_SCOPE_AGENT);
            }
        }
        while (__hip_atomic_load(gen, __ATOMIC_RELAXED, __HIP_MEMORY_SCOPE_AGENT) < my_gen)
            __builtin_amdgcn_s_sleep(2);
        (void)__hip_atomic_load(gen, __ATOMIC_ACQUIRE, __HIP_MEMORY_SCOPE_AGENT);
    }
    __syncthreads();
}

// ---- layer 0 tile: x16 fp16 [NN,64] -> out8 = fp8(lrelu((A_hat x) @ (64*W0) + 64*b0)) ----
__device__ __forceinline__ void layer0_tile(
    const __half* __restrict__ x, const int* __restrict__ row_ptr,
    const int2* __restrict__ csr, const float* __restrict__ dinv,
    const __half* __restrict__ Wt, const float* __restrict__ bias,
    unsigned char* __restrict__ out8, int node0, int tid, _Float16* hsF) {
    {
        int nl = tid >> 4;
        int node = node0 + nl;
        int c = (tid & 15) * 4;
        float di = dinv[node];
        float w0 = di * di;
        float4 hv = loadh4(&x[(size_t)node * 64 + c]);
        float4 acc[8];
        acc[0] = make_float4(hv.x * w0, hv.y * w0, hv.z * w0, hv.w * w0);
        #pragma unroll
        for (int j = 1; j < 8; j++) acc[j] = make_float4(0.f, 0.f, 0.f, 0.f);
        int e = row_ptr[node];
        int e1 = row_ptr[node + 1];
        for (; e + 8 <= e1; e += 8) {
            int2 sw[8];
            #pragma unroll
            for (int j = 0; j < 8; j++) sw[j] = csr[e + j];
            float4 v[8];
            #pragma unroll
            for (int j = 0; j < 8; j++) v[j] = loadh4(&x[(size_t)sw[j].x * 64 + c]);
            #pragma unroll
            for (int j = 0; j < 8; j++) acc[j] = fma4(v[j], __int_as_float(sw[j].y), acc[j]);
        }
        for (; e < e1; ++e) {
            int2 sw = csr[e];
            float4 v = loadh4(&x[(size_t)sw.x * 64 + c]);
            acc[0] = fma4(v, __int_as_float(sw.y), acc[0]);
        }
        #pragma unroll
        for (int j = 1; j < 8; j++) {
            acc[0].x += acc[j].x;
            acc[0].y += acc[j].y;
            acc[0].z += acc[j].z;
            acc[0].w += acc[j].w;
        }
        int ks = c >> 5, quad = (c >> 3) & 3, jj = c & 7;
        __half2 p0 = __floats2half2_rn(acc[0].x, acc[0].y);
        __half2 p1 = __floats2half2_rn(acc[0].z, acc[0].w);
        uint2 pk;
        pk.x = *(unsigned int*)&p0;
        pk.y = *(unsigned int*)&p1;
        *(uint2*)&hsF[((ks * 4 + quad) * 16 + nl) * 8 + jj] = pk;
    }
    __syncthreads();
    int wave = tid >> 6, lane = tid & 63, quad = lane >> 4, ln = lane & 15;
    half8 afrag[2];
    #pragma unroll
    for (int ks = 0; ks < 2; ks++)
        afrag[ks] = *(const half8*)&hsF[((ks * 4 + quad) * 16 + ln) * 8];
    #pragma unroll
    for (int tc = 0; tc < 2; tc++) {
        int tt = wave + tc * 4;
        floatx4 acc = (floatx4){0.f, 0.f, 0.f, 0.f};
        #pragma unroll
        for (int ks = 0; ks < 2; ks++) {
            half8 b = *(const half8*)&Wt[(size_t)(tt * 16 + ln) * 64 + ks * 32 + quad * 8];
            acc = __builtin_amdgcn_mfma_f32_16x16x32_f16(afrag[ks], b, acc, 0, 0, 0);
        }
        int col = tt * 16 + ln;
        float bb = bias[col];
        #pragma unroll
        for (int r = 0; r < 4; r++) {
            int row = node0 + quad * 4 + r;
            stnt_f8(&out8[(size_t)row * 128 + col], lrelu(acc[r] + bb));
        }
    }
    __syncthreads();
}

// ---- hidden tile: h fp8 [NN,128] -> out8 = fp8(lrelu((A_hat h) @ Wt + bias)) ----
template <bool LAST>
__device__ __forceinline__ void layerh_tile(
    const unsigned char* __restrict__ h, const int* __restrict__ row_ptr,
    const int2* __restrict__ csr, const float* __restrict__ dinv,
    const __half* __restrict__ Wt, const float* __restrict__ bias,
    unsigned char* __restrict__ out8, const float* __restrict__ Wout,
    float* __restrict__ u, int node0, int tid, _Float16* hsF, float* uaccS) {
    {
        int nl = tid >> 4;
        int node = node0 + nl;
        int c = (tid & 15) * 8;
        float di = dinv[node];
        float w0 = di * di;
        float4 hlo, hhi;
        loadf8x8(&h[(size_t)node * 128 + c], &hlo, &hhi);
        float4 acc[4][2];
        acc[0][0] = make_float4(hlo.x * w0, hlo.y * w0, hlo.z * w0, hlo.w * w0);
        acc[0][1] = make_float4(hhi.x * w0, hhi.y * w0, hhi.z * w0, hhi.w * w0);
        #pragma unroll
        for (int j = 1; j < 4; j++) {
            acc[j][0] = make_float4(0.f, 0.f, 0.f, 0.f);
            acc[j][1] = make_float4(0.f, 0.f, 0.f, 0.f);
        }
        int e = row_ptr[node];
        int e1 = row_ptr[node + 1];
        for (; e + 8 <= e1; e += 8) {
            int2 sw[8];
            #pragma unroll
            for (int j = 0; j < 8; j++) sw[j] = csr[e + j];
            uint2 raw[8];
            #pragma unroll
            for (int j = 0; j < 8; j++) raw[j] = *(const uint2*)&h[(size_t)sw[j].x * 128 + c];
            #pragma unroll
            for (int j = 0; j < 8; j++) {
                float w = __int_as_float(sw[j].y);
                float4 vlo, vhi;
                cvtf8x8(raw[j], &vlo, &vhi);
                acc[j & 3][0] = fma4(vlo, w, acc[j & 3][0]);
                acc[j & 3][1] = fma4(vhi, w, acc[j & 3][1]);
            }
        }
        for (; e + 4 <= e1; e += 4) {
            int2 sw[4];
            #pragma unroll
            for (int j = 0; j < 4; j++) sw[j] = csr[e + j];
            uint2 raw[4];
            #pragma unroll
            for (int j = 0; j < 4; j++) raw[j] = *(const uint2*)&h[(size_t)sw[j].x * 128 + c];
            #pragma unroll
            for (int j = 0; j < 4; j++) {
                float w = __int_as_float(sw[j].y);
                float4 vlo, vhi;
                cvtf8x8(raw[j], &vlo, &vhi);
                acc[j][0] = fma4(vlo, w, acc[j][0]);
                acc[j][1] = fma4(vhi, w, acc[j][1]);
            }
        }
        for (; e < e1; ++e) {
            int2 sw = csr[e];
            float4 vlo, vhi;
            loadf8x8(&h[(size_t)sw.x * 128 + c], &vlo, &vhi);
            float w = __int_as_float(sw.y);
            acc[0][0] = fma4(vlo, w, acc[0][0]);
            acc[0][1] = fma4(vhi, w, acc[0][1]);
        }
        #pragma unroll
        for (int j = 1; j < 4; j++) {
            acc[0][0].x += acc[j][0].x; acc[0][0].y += acc[j][0].y;
            acc[0][0].z += acc[j][0].z; acc[0][0].w += acc[j][0].w;
            acc[0][1].x += acc[j][1].x; acc[0][1].y += acc[j][1].y;
            acc[0][1].z += acc[j][1].z; acc[0][1].w += acc[j][1].w;
        }
        int ks = c >> 5, quad = (c >> 3) & 3;
        __half2 p0 = __floats2half2_rn(acc[0][0].x, acc[0][0].y);
        __half2 p1 = __floats2half2_rn(acc[0][0].z, acc[0][0].w);
        __half2 p2 = __floats2half2_rn(acc[0][1].x, acc[0][1].y);
        __half2 p3 = __floats2half2_rn(acc[0][1].z, acc[0][1].w);
        uint4 pk;
        pk.x = *(unsigned int*)&p0;
        pk.y = *(unsigned int*)&p1;
        pk.z = *(unsigned int*)&p2;
        pk.w = *(unsigned int*)&p3;
        *(uint4*)&hsF[((ks * 4 + quad) * 16 + nl) * 8] = pk;
    }
    __syncthreads();
    int wave = tid >> 6, lane = tid & 63, quad = lane >> 4, ln = lane & 15;
    half8 afrag[4];
    #pragma unroll
    for (int ks = 0; ks < 4; ks++)
        afrag[ks] = *(const half8*)&hsF[((ks * 4 + quad) * 16 + ln) * 8];

    float up[4][3];
    if (LAST) {
        #pragma unroll
        for (int r = 0; r < 4; r++)
            #pragma unroll
            for (int cc = 0; cc < 3; cc++) up[r][cc] = 0.f;
    }

    #pragma unroll
    for (int tc = 0; tc < 2; tc++) {
        int tt = wave + tc * 4;
        floatx4 acc = (floatx4){0.f, 0.f, 0.f, 0.f};
        #pragma unroll
        for (int ks = 0; ks < 4; ks++) {
            half8 b = *(const half8*)&Wt[(size_t)(tt * 16 + ln) * 128 + ks * 32 + quad * 8];
            acc = __builtin_amdgcn_mfma_f32_16x16x32_f16(afrag[ks], b, acc, 0, 0, 0);
        }
        int col = tt * 16 + ln;
        float bb = bias[col];
        if (LAST) {
            float w0o = Wout[col * 3 + 0];
            float w1o = Wout[col * 3 + 1];
            float w2o = Wout[col * 3 + 2];
            #pragma unroll
            for (int r = 0; r < 4; r++) {
                float hv = lrelu(acc[r] + bb);
                up[r][0] = fmaf(hv, w0o, up[r][0]);
                up[r][1] = fmaf(hv, w1o, up[r][1]);
                up[r][2] = fmaf(hv, w2o, up[r][2]);
            }
        } else {
            #pragma unroll
            for (int r = 0; r < 4; r++) {
                int row = node0 + quad * 4 + r;
                stnt_f8(&out8[(size_t)row * 128 + col], lrelu(acc[r] + bb));
            }
        }
    }

    if (LAST) {
        #pragma unroll
        for (int m = 1; m < 16; m <<= 1) {
            #pragma unroll
            for (int r = 0; r < 4; r++) {
                #pragma unroll
                for (int cc = 0; cc < 3; cc++)
                    up[r][cc] += __shfl_xor(up[r][cc], m);
            }
        }
        if (ln == 0) {
            #pragma unroll
            for (int r = 0; r < 4; r++) {
                #pragma unroll
                for (int cc = 0; cc < 3; cc++)
                    uaccS[(wave * 16 + quad * 4 + r) * 3 + cc] = up[r][cc];
            }
        }
        __syncthreads();
        if (tid < 48) {
            int row = tid / 3, cc = tid % 3;
            float s = (uaccS[(0 * 16 + row) * 3 + cc] + uaccS[(1 * 16 + row) * 3 + cc]) +
                      (uaccS[(2 * 16 + row) * 3 + cc] + uaccS[(3 * 16 + row) * 3 + cc]);
            u[(size_t)(node0 + row) * 3 + cc] = s;
        }
    }
    __syncthreads();
}

// ================= mega-kernel v2: 1536 blocks x 256 thr, ticket tiles =================
__launch_bounds__(NTHR, 6)
__global__ void k_mega(const float* __restrict__ x, const int* __restrict__ ei,
                       const float* __restrict__ W0, const float* __restrict__ b0,
                       const float* __restrict__ Wh, const float* __restrict__ bh,
                       const float* __restrict__ Wout, const float* __restrict__ bout,
                       float* __restrict__ out,
                       float* __restrict__ u, unsigned char* __restrict__ bufB8,
                       unsigned char* __restrict__ bufC8, __half* __restrict__ x16,
                       __half* __restrict__ W0t, __half* __restrict__ Wht,
                       float* __restrict__ bs, float* __restrict__ dinv,
                       int* __restrict__ cnt, int* __restrict__ bar,
                       int* __restrict__ row_ptr, int* __restrict__ cursor,
                       int2* __restrict__ csr) {
    __shared__ _Float16 hsF[4 * 4 * 16 * 8];  // 4 KB
    __shared__ float uaccS[4 * 16 * 3];
    __shared__ int sscan[NTHR];
    __shared__ int t_sh;

    int tid = threadIdx.x;
    int bid = blockIdx.x;
    int g0 = bid * NTHR + tid;
    int bgen = 0;
    int* tick = bar;  // tickets live at bar[0..7]

    // ---- P0: degree-count atomics + weight/bias converts (cnt+bar zeroed by host memset)
    for (int g = g0; g < NE; g += GSZ) atomicAdd(&cnt[ei[NE + g]], 1);
    if (g0 < 8192) {                       // W0 [64,128] -> W0t [128n][64k], *G1=64
        int k = g0 >> 7, n = g0 & 127;
        W0t[n * 64 + k] = __float2half(W0[g0] * 64.0f);
    } else if (g0 < 8192 + 98304) {        // Wh [6][128,128] -> Wht [6][128n][128k], *2
        int j = g0 - 8192;
        int l = j >> 14;
        int r = j & 16383;
        int k = r >> 7, n = r & 127;
        Wht[l * 16384 + n * 128 + k] = __float2half(Wh[j] * 2.0f);
    } else if (g0 < 8192 + 98304 + 896) {  // biases: b0*64 | bh[i]*2^(7+i)
        int j = g0 - 8192 - 98304;
        float sc;
        if (j < 128) sc = 64.0f;
        else sc = (float)(1 << (7 + ((j - 128) >> 7)));
        bs[j] = (j < 128 ? b0[j] : bh[j - 128]) * sc;
    }
    gbar(bar, bid, ++bgen);

    // ---- P1: block 0 scans counts -> row_ptr/cursor/dinv  ||  others convert x->fp16
    if (bid == 0) {
        const int CH = 118;  // 256*118 = 30208 >= NN
        int base = tid * CH;
        int s = 0;
        for (int i = 0; i < CH; ++i) {
            int idx = base + i;
            if (idx < NN) s += cnt[idx];
        }
        sscan[tid] = s;
        __syncthreads();
        for (int off = 1; off < NTHR; off <<= 1) {
            int t = (tid >= off) ? sscan[tid - off] : 0;
            __syncthreads();
            sscan[tid] += t;
            __syncthreads();
        }
        int run = sscan[tid] - s;  // exclusive prefix
        for (int i = 0; i < CH; ++i) {
            int idx = base + i;
            if (idx < NN) {
                int cv = cnt[idx];
                row_ptr[idx] = run;
                cursor[idx] = run;
                dinv[idx] = 1.0f / sqrtf((float)(cv + 1));  // +1 self loop
                run += cv;
            }
        }
        if (tid == NTHR - 1) row_ptr[NN] = sscan[NTHR - 1];
    } else {
        // x -> fp16: NN*64/4 = 480000 float4 elements over 1535 blocks (2 passes)
        for (int g = (bid - 1) * NTHR + tid; g < NN * 16; g += (NBLK - 1) * NTHR) {
            float4 v = *(const float4*)&x[(size_t)g * 4];
            __half2 a = __floats2half2_rn(v.x, v.y);
            __half2 b = __floats2half2_rn(v.z, v.w);
            uint2 pk;
            pk.x = *(unsigned int*)&a;
            pk.y = *(unsigned int*)&b;
            *(uint2*)&x16[(size_t)g * 4] = pk;
        }
    }
    gbar(bar, bid, ++bgen);

    // ---- P2: CSR fill
    for (int g = g0; g < NE; g += GSZ) {
        int s = ei[g];
        int d = ei[NE + g];
        int pos = atomicAdd(&cursor[d], 1);
        float w = dinv[s] * dinv[d];
        csr[pos] = make_int2(s, __float_as_int(w));
    }
    gbar(bar, bid, ++bgen);

    // ---- P3: layer 0 (ticket queue, load-balanced)
    for (;;) {
        __syncthreads();
        if (tid == 0) t_sh = atomicAdd(&tick[0], 1);
        __syncthreads();
        int t = t_sh;
        if (t >= NTILE) break;
        layer0_tile(x16, row_ptr, csr, dinv, W0t, bs, bufB8, t * 16, tid, hsF);
    }
    gbar(bar, bid, ++bgen);

    // ---- P4..P9: hidden layers (5 plain + 1 LAST with fused Wout)
    unsigned char* hin = bufB8;
    unsigned char* hout = bufC8;
    for (int l = 0; l < 5; ++l) {
        for (;;) {
            __syncthreads();
            if (tid == 0) t_sh = atomicAdd(&tick[1 + l], 1);
            __syncthreads();
            int t = t_sh;
            if (t >= NTILE) break;
            layerh_tile<false>(hin, row_ptr, csr, dinv, Wht + (size_t)l * 16384,
                               bs + 128 + (size_t)l * 128, hout, Wout, u, t * 16,
                               tid, hsF, uaccS);
        }
        gbar(bar, bid, ++bgen);
        unsigned char* tmp = hin; hin = hout; hout = tmp;
    }
    for (;;) {
        __syncthreads();
        if (tid == 0) t_sh = atomicAdd(&tick[6], 1);
        __syncthreads();
        int t = t_sh;
        if (t >= NTILE) break;
        layerh_tile<true>(hin, row_ptr, csr, dinv, Wht + (size_t)5 * 16384,
                          bs + 128 + (size_t)5 * 128, hout, Wout, u, t * 16,
                          tid, hsF, uaccS);
    }
    gbar(bar, bid, ++bgen);

    // ---- P10: final aggregate (3 ch), unscale, + bias, tanh*0.5
    {
        int node = g0;
        if (node < NN) {
            float di = dinv[node], w0 = di * di;
            float s0 = u[(size_t)node * 3 + 0] * w0;
            float s1 = u[(size_t)node * 3 + 1] * w0;
            float s2 = u[(size_t)node * 3 + 2] * w0;
            float b0a = 0.f, b1a = 0.f, b2a = 0.f;
            int e = row_ptr[node];
            int e1 = row_ptr[node + 1];
            for (; e + 2 <= e1; e += 2) {
                int2 swa = csr[e], swb = csr[e + 1];
                float wa = __int_as_float(swa.y), wb = __int_as_float(swb.y);
                const float* ua = &u[(size_t)swa.x * 3];
                const float* ub = &u[(size_t)swb.x * 3];
                s0 = fmaf(ua[0], wa, s0);
                s1 = fmaf(ua[1], wa, s1);
                s2 = fmaf(ua[2], wa, s2);
                b0a = fmaf(ub[0], wb, b0a);
                b1a = fmaf(ub[1], wb, b1a);
                b2a = fmaf(ub[2], wb, b2a);
            }
            for (; e < e1; ++e) {
                int2 sw = csr[e];
                float w = __int_as_float(sw.y);
                const float* us = &u[(size_t)sw.x * 3];
                s0 = fmaf(us[0], w, s0);
                s1 = fmaf(us[1], w, s1);
                s2 = fmaf(us[2], w, s2);
            }
            out[(size_t)node * 3 + 0] = tanhf((s0 + b0a) * INVSCALE + bout[0]) * 0.5f;
            out[(size_t)node * 3 + 1] = tanhf((s1 + b1a) * INVSCALE + bout[1]) * 0.5f;
            out[(size_t)node * 3 + 2] = tanhf((s2 + b2a) * INVSCALE + bout[2]) * 0.5f;
        }
    }
}

// ---------------- launch: 2 dispatches total ----------------

extern "C" void kernel_launch(void* const* d_in, const int* in_sizes, int n_in,
                              void* d_out, int out_size, void* d_ws, size_t ws_size,
                              hipStream_t stream) {
    const float* x        = (const float*)d_in[0];
    const int*   ei       = (const int*)d_in[1];   // int32: [2, NE] row-major
    const float* W0       = (const float*)d_in[2];
    const float* b0       = (const float*)d_in[3];
    const float* Wh       = (const float*)d_in[4];
    const float* bh       = (const float*)d_in[5];
    const float* Wout     = (const float*)d_in[6];
    const float* bout     = (const float*)d_in[7];
    float* out            = (float*)d_out;

    char* ws = (char*)d_ws;
    float*  bufA   = (float*)(ws + 0);                       // u (NN x 3 fp32)
    unsigned char* bufB8 = (unsigned char*)(ws + 15360000);  // NN*128 fp8
    unsigned char* bufC8 = (unsigned char*)(ws + 23040000);  // NN*128 fp8
    __half* x16    = (__half*)(ws + 30720000);               // NN*64 fp16
    __half* W0t16  = (__half*)(ws + 34560000);               // 128*64 fp16
    __half* Wht16  = (__half*)(ws + 34576384);               // 6*128*128 fp16
    float*  bs     = (float*)(ws + 34772992);                // 7*128 fp32 scaled biases
    float*  dinv   = (float*)(ws + 34776576);                // NN floats
    int*    cnt    = (int*)  (ws + 34896576);                // NN ints
    int*    bar    = (int*)  (ws + 35016576);                // 4KB: tickets+barrier state
    int*    row_ptr= (int*)  (ws + 35020672);                // NN+1 ints
    int*    cursor = (int*)  (ws + 35140736);                // NN ints
    int2*   csr    = (int2*) (ws + 35260736);                // NE int2

    // zero cnt + tickets + barrier state in ONE memset (adjacent regions)
    hipMemsetAsync(cnt, 0, 120000 + 4096, stream);
    k_mega<<<NBLK, NTHR, 0, stream>>>(x, ei, W0, b0, Wh, bh, Wout, bout, out,
                                      bufA, bufB8, bufC8, x16, W0t16, Wht16, bs,
                                      dinv, cnt, bar, row_ptr, cursor, csr);
}

// Round 5
// 324.039 us; speedup vs baseline: 3.5550x; 3.5550x over previous
//
#include <hip/hip_runtime.h>
#include <hip/hip_fp16.h>
#include <math.h>

#define NN 30000
#define NE 480000
#define NTILE 1875          // NN/16 node-tiles
#define INVSCALE (1.0f / 4096.0f)

// R18: back to the known-good multi-dispatch skeleton (R14, 297us) after the
// persistent-kernel arc (R15 604us / R16 1152us / R17 deadlock-crash) showed
// grid-sync + co-residency coupling is fragile. Attack the ~220us of kernel work:
// hidden layers are serial-latency-bound in the edge loop (~2-3 dependent 500cy
// round trips/node). Fixes: (1) 512-thr blocks, 32 thr/node = 2 edge-groups x 16
// ch-lanes, partials merged via shfl_xor(,16) -> serial chain halved; (2) masked
// tail chunks (zero-weight lanes) -> tails gather in parallel too; (3) scan1+scan3
// merged into one single-block kernel (13 -> 11 dispatches). fp8 h + folded
// per-layer power-of-2 scales kept (absmax 6.1e-5 verified R1-R3).

typedef _Float16 half8 __attribute__((ext_vector_type(8)));
typedef float floatx4 __attribute__((ext_vector_type(4)));
typedef float floatx2 __attribute__((ext_vector_type(2)));

__device__ __forceinline__ float lrelu(float v) { return v > 0.0f ? v : v * 0.02f; }

__device__ __forceinline__ float4 fma4(float4 v, float w, float4 a) {
    a.x = fmaf(v.x, w, a.x);
    a.y = fmaf(v.y, w, a.y);
    a.z = fmaf(v.z, w, a.z);
    a.w = fmaf(v.w, w, a.w);
    return a;
}

__device__ __forceinline__ float4 cvth4(uint2 raw) {
    float2 f0 = __half22float2(*(__half2*)&raw.x);
    float2 f1 = __half22float2(*(__half2*)&raw.y);
    return make_float4(f0.x, f0.y, f1.x, f1.y);
}

__device__ __forceinline__ void cvtf8x8(uint2 raw, float4* lo, float4* hi) {
    floatx2 a = __builtin_amdgcn_cvt_pk_f32_fp8(raw.x, false);
    floatx2 b = __builtin_amdgcn_cvt_pk_f32_fp8(raw.x, true);
    floatx2 c = __builtin_amdgcn_cvt_pk_f32_fp8(raw.y, false);
    floatx2 d = __builtin_amdgcn_cvt_pk_f32_fp8(raw.y, true);
    *lo = make_float4(a.x, a.y, b.x, b.y);
    *hi = make_float4(c.x, c.y, d.x, d.y);
}

__device__ __forceinline__ void stnt_f8(unsigned char* p, float v) {
    int pk = __builtin_amdgcn_cvt_pk_fp8_f32(v, v, 0, false);  // RNE, saturates
    __builtin_nontemporal_store((unsigned char)pk, p);
}

// cross-edge-group combine: groups sit 16 lanes apart in the same wave
__device__ __forceinline__ float4 xadd16(float4 a) {
    a.x += __shfl_xor(a.x, 16);
    a.y += __shfl_xor(a.y, 16);
    a.z += __shfl_xor(a.z, 16);
    a.w += __shfl_xor(a.w, 16);
    return a;
}

// ---------------- CSR build (+ fused weight convert + x->fp16) ----------------

__global__ void k_count(const int* __restrict__ ei, int* __restrict__ cnt,
                        const float* __restrict__ W0, const float* __restrict__ Wh,
                        const float* __restrict__ b0, const float* __restrict__ bh,
                        const float* __restrict__ x,
                        __half* __restrict__ W0t, __half* __restrict__ Wht,
                        float* __restrict__ bs, __half* __restrict__ x16) {
    int g = blockIdx.x * 256 + threadIdx.x;
    if (g < NE) atomicAdd(&cnt[ei[NE + g]], 1);
    {   // x -> fp16: 1.92M elements, 4 per thread
        float4 v = *(const float4*)&x[(size_t)g * 4];
        __half2 a = __floats2half2_rn(v.x, v.y);
        __half2 b = __floats2half2_rn(v.z, v.w);
        uint2 pk;
        pk.x = *(unsigned int*)&a;
        pk.y = *(unsigned int*)&b;
        *(uint2*)&x16[(size_t)g * 4] = pk;
    }
    if (g < 8192) {                       // W0 [64,128] -> W0t [128n][64k], *G1=64
        int k = g >> 7, n = g & 127;
        W0t[n * 64 + k] = __float2half(W0[g] * 64.0f);
    } else if (g < 8192 + 98304) {        // Wh [6][128,128] -> Wht [6][128n][128k], *2
        int j = g - 8192;
        int l = j >> 14;
        int r = j & 16383;
        int k = r >> 7, n = r & 127;
        Wht[l * 16384 + n * 128 + k] = __float2half(Wh[j] * 2.0f);
    } else if (g < 8192 + 98304 + 896) {  // biases: b0*64 | bh[i]*2^(7+i)
        int j = g - 8192 - 98304;
        float sc;
        if (j < 128) sc = 64.0f;
        else sc = (float)(1 << (7 + ((j - 128) >> 7)));
        bs[j] = (j < 128 ? b0[j] : bh[j - 128]) * sc;
    }
}

// single-block merged scan: cnt -> row_ptr/cursor/dinv (replaces scan1+scan3)
__global__ void k_scan(const int* __restrict__ cnt, int* __restrict__ row_ptr,
                       int* __restrict__ cursor, float* __restrict__ dinv) {
    __shared__ int part[1024];
    int tid = threadIdx.x;
    const int CH = 32;  // 1024*32 = 32768 >= NN
    int base = tid * CH;
    int s = 0;
    #pragma unroll
    for (int i = 0; i < CH; i += 4) {
        int idx = base + i;
        if (idx < NN) {
            int4 v = *(const int4*)&cnt[idx];
            s += v.x + v.y + v.z + v.w;
        }
    }
    part[tid] = s;
    __syncthreads();
    for (int off = 1; off < 1024; off <<= 1) {
        int t = (tid >= off) ? part[tid - off] : 0;
        __syncthreads();
        part[tid] += t;
        __syncthreads();
    }
    int run = part[tid] - s;  // exclusive prefix
    #pragma unroll
    for (int i = 0; i < CH; i += 4) {
        int idx = base + i;
        if (idx < NN) {
            int4 v = *(const int4*)&cnt[idx];
            int4 rp;
            rp.x = run;
            rp.y = rp.x + v.x;
            rp.z = rp.y + v.y;
            rp.w = rp.z + v.z;
            run = rp.w + v.w;
            *(int4*)&row_ptr[idx] = rp;
            *(int4*)&cursor[idx] = rp;
            float4 dv;
            dv.x = 1.0f / sqrtf((float)(v.x + 1));  // +1 self loop
            dv.y = 1.0f / sqrtf((float)(v.y + 1));
            dv.z = 1.0f / sqrtf((float)(v.z + 1));
            dv.w = 1.0f / sqrtf((float)(v.w + 1));
            *(float4*)&dinv[idx] = dv;
        }
    }
    if (tid == 1023) row_ptr[NN] = part[1023];
}

__global__ void k_fill(const int* __restrict__ ei, const float* __restrict__ dinv,
                       int* __restrict__ cursor, int2* __restrict__ csr) {
    int e = blockIdx.x * 256 + threadIdx.x;
    if (e < NE) {
        int s = ei[e];
        int d = ei[NE + e];
        int pos = atomicAdd(&cursor[d], 1);
        float w = dinv[s] * dinv[d];
        csr[pos] = make_int2(s, __float_as_int(w));
    }
}

// ====== fused layer kernels: 512 thr, 16 nodes, 32 thr/node (2 edge-groups) ======
// Agg: group sub handles 8-edge chunks at e0+sub*8, e0+sub*8+16, ... with masked
// weights (parallel tails). Partials merge via shfl_xor(,16). MFMA: 8 waves, wave w
// computes output cols w*16..w*16+15.

// ---- layer 0: x16 fp16 [NN,64] -> out8 = fp8(lrelu((A_hat x) @ (64*W0) + 64*b0)) ----
__launch_bounds__(512)
__global__ void k_layer0(const __half* __restrict__ x, const int* __restrict__ row_ptr,
                         const int2* __restrict__ csr, const float* __restrict__ dinv,
                         const __half* __restrict__ Wt, const float* __restrict__ bias,
                         unsigned char* __restrict__ out8) {
    __shared__ _Float16 hsF[2 * 4 * 16 * 8];  // 2 KB
    int tid = threadIdx.x;
    int node0 = blockIdx.x * 16;
    {
        int nl = tid >> 5;            // node 0..15
        int sub = (tid >> 4) & 1;     // edge-group
        int c = (tid & 15) * 4;       // 4 fp16 ch / lane
        int node = node0 + nl;
        float4 acc[4];
        #pragma unroll
        for (int j = 0; j < 4; j++) acc[j] = make_float4(0.f, 0.f, 0.f, 0.f);
        if (sub == 0) {
            float di = dinv[node];
            float w0 = di * di;
            float4 hv = cvth4(*(const uint2*)&x[(size_t)node * 64 + c]);
            acc[0] = make_float4(hv.x * w0, hv.y * w0, hv.z * w0, hv.w * w0);
        }
        int e0 = row_ptr[node];
        int e1 = row_ptr[node + 1];
        for (int ee = e0 + sub * 8; ee < e1; ee += 16) {
            int2 sw[8];
            uint2 raw[8];
            #pragma unroll
            for (int j = 0; j < 8; j++) {
                int idx = (ee + j < e1) ? ee + j : e1 - 1;
                sw[j] = csr[idx];
            }
            #pragma unroll
            for (int j = 0; j < 8; j++)
                raw[j] = *(const uint2*)&x[(size_t)sw[j].x * 64 + c];
            #pragma unroll
            for (int j = 0; j < 8; j++) {
                float w = (ee + j < e1) ? __int_as_float(sw[j].y) : 0.f;
                acc[j & 3] = fma4(cvth4(raw[j]), w, acc[j & 3]);
            }
        }
        acc[0].x += acc[1].x + acc[2].x + acc[3].x;
        acc[0].y += acc[1].y + acc[2].y + acc[3].y;
        acc[0].z += acc[1].z + acc[2].z + acc[3].z;
        acc[0].w += acc[1].w + acc[2].w + acc[3].w;
        acc[0] = xadd16(acc[0]);      // merge the two edge-groups
        if (sub == 0) {
            int ks = c >> 5, quad = (c >> 3) & 3, jj = c & 7;
            __half2 p0 = __floats2half2_rn(acc[0].x, acc[0].y);
            __half2 p1 = __floats2half2_rn(acc[0].z, acc[0].w);
            uint2 pk;
            pk.x = *(unsigned int*)&p0;
            pk.y = *(unsigned int*)&p1;
            *(uint2*)&hsF[((ks * 4 + quad) * 16 + nl) * 8 + jj] = pk;
        }
    }
    __syncthreads();
    int tt = tid >> 6, lane = tid & 63, quad = lane >> 4, ln = lane & 15;
    half8 afrag[2];
    #pragma unroll
    for (int ks = 0; ks < 2; ks++)
        afrag[ks] = *(const half8*)&hsF[((ks * 4 + quad) * 16 + ln) * 8];
    floatx4 acc = (floatx4){0.f, 0.f, 0.f, 0.f};
    #pragma unroll
    for (int ks = 0; ks < 2; ks++) {
        half8 b = *(const half8*)&Wt[(size_t)(tt * 16 + ln) * 64 + ks * 32 + quad * 8];
        acc = __builtin_amdgcn_mfma_f32_16x16x32_f16(afrag[ks], b, acc, 0, 0, 0);
    }
    int col = tt * 16 + ln;
    float bb = bias[col];
    #pragma unroll
    for (int r = 0; r < 4; r++) {
        int row = node0 + quad * 4 + r;
        stnt_f8(&out8[(size_t)row * 128 + col], lrelu(acc[r] + bb));
    }
}

// ---- hidden layer: h fp8 [NN,128] -> out8 = fp8(lrelu((A_hat h) @ Wt + bias)) ----
// LAST=true: u = h7' @ Wout computed in-block; h7' never hits global.
template <bool LAST>
__launch_bounds__(512)
__global__ void k_layer_h(const unsigned char* __restrict__ h, const int* __restrict__ row_ptr,
                          const int2* __restrict__ csr, const float* __restrict__ dinv,
                          const __half* __restrict__ Wt, const float* __restrict__ bias,
                          unsigned char* __restrict__ out8, const float* __restrict__ Wout,
                          float* __restrict__ u) {
    __shared__ _Float16 hsF[4 * 4 * 16 * 8];  // 4 KB
    __shared__ float uaccS[8][16][3];         // cross-wave u partials (LAST only)
    int tid = threadIdx.x;
    int node0 = blockIdx.x * 16;
    {
        int nl = tid >> 5;            // node 0..15
        int sub = (tid >> 4) & 1;     // edge-group
        int c = (tid & 15) * 8;       // 8 fp8 ch / lane
        int node = node0 + nl;
        float4 acc[2][2];
        #pragma unroll
        for (int j = 0; j < 2; j++) {
            acc[j][0] = make_float4(0.f, 0.f, 0.f, 0.f);
            acc[j][1] = make_float4(0.f, 0.f, 0.f, 0.f);
        }
        if (sub == 0) {
            float di = dinv[node];
            float w0 = di * di;
            float4 hlo, hhi;
            cvtf8x8(*(const uint2*)&h[(size_t)node * 128 + c], &hlo, &hhi);
            acc[0][0] = make_float4(hlo.x * w0, hlo.y * w0, hlo.z * w0, hlo.w * w0);
            acc[0][1] = make_float4(hhi.x * w0, hhi.y * w0, hhi.z * w0, hhi.w * w0);
        }
        int e0 = row_ptr[node];
        int e1 = row_ptr[node + 1];
        for (int ee = e0 + sub * 8; ee < e1; ee += 16) {
            int2 sw[8];
            uint2 raw[8];
            #pragma unroll
            for (int j = 0; j < 8; j++) {
                int idx = (ee + j < e1) ? ee + j : e1 - 1;
                sw[j] = csr[idx];
            }
            #pragma unroll
            for (int j = 0; j < 8; j++)
                raw[j] = *(const uint2*)&h[(size_t)sw[j].x * 128 + c];
            #pragma unroll
            for (int j = 0; j < 8; j++) {
                float w = (ee + j < e1) ? __int_as_float(sw[j].y) : 0.f;
                float4 vlo, vhi;
                cvtf8x8(raw[j], &vlo, &vhi);
                acc[j & 1][0] = fma4(vlo, w, acc[j & 1][0]);
                acc[j & 1][1] = fma4(vhi, w, acc[j & 1][1]);
            }
        }
        acc[0][0].x += acc[1][0].x; acc[0][0].y += acc[1][0].y;
        acc[0][0].z += acc[1][0].z; acc[0][0].w += acc[1][0].w;
        acc[0][1].x += acc[1][1].x; acc[0][1].y += acc[1][1].y;
        acc[0][1].z += acc[1][1].z; acc[0][1].w += acc[1][1].w;
        acc[0][0] = xadd16(acc[0][0]);   // merge the two edge-groups
        acc[0][1] = xadd16(acc[0][1]);
        if (sub == 0) {
            int ks = c >> 5, quad = (c >> 3) & 3;
            __half2 p0 = __floats2half2_rn(acc[0][0].x, acc[0][0].y);
            __half2 p1 = __floats2half2_rn(acc[0][0].z, acc[0][0].w);
            __half2 p2 = __floats2half2_rn(acc[0][1].x, acc[0][1].y);
            __half2 p3 = __floats2half2_rn(acc[0][1].z, acc[0][1].w);
            uint4 pk;
            pk.x = *(unsigned int*)&p0;
            pk.y = *(unsigned int*)&p1;
            pk.z = *(unsigned int*)&p2;
            pk.w = *(unsigned int*)&p3;
            *(uint4*)&hsF[((ks * 4 + quad) * 16 + nl) * 8] = pk;
        }
    }
    __syncthreads();
    int tt = tid >> 6, lane = tid & 63, quad = lane >> 4, ln = lane & 15;
    half8 afrag[4];
    #pragma unroll
    for (int ks = 0; ks < 4; ks++)
        afrag[ks] = *(const half8*)&hsF[((ks * 4 + quad) * 16 + ln) * 8];

    floatx4 acc = (floatx4){0.f, 0.f, 0.f, 0.f};
    #pragma unroll
    for (int ks = 0; ks < 4; ks++) {
        half8 b = *(const half8*)&Wt[(size_t)(tt * 16 + ln) * 128 + ks * 32 + quad * 8];
        acc = __builtin_amdgcn_mfma_f32_16x16x32_f16(afrag[ks], b, acc, 0, 0, 0);
    }
    int col = tt * 16 + ln;
    float bb = bias[col];
    if (LAST) {
        float up[4][3];
        float w0o = Wout[col * 3 + 0];
        float w1o = Wout[col * 3 + 1];
        float w2o = Wout[col * 3 + 2];
        #pragma unroll
        for (int r = 0; r < 4; r++) {
            float hv = lrelu(acc[r] + bb);
            up[r][0] = hv * w0o;
            up[r][1] = hv * w1o;
            up[r][2] = hv * w2o;
        }
        #pragma unroll
        for (int m = 1; m < 16; m <<= 1) {
            #pragma unroll
            for (int r = 0; r < 4; r++) {
                #pragma unroll
                for (int cc = 0; cc < 3; cc++)
                    up[r][cc] += __shfl_xor(up[r][cc], m);
            }
        }
        if (ln == 0) {
            #pragma unroll
            for (int r = 0; r < 4; r++) {
                #pragma unroll
                for (int cc = 0; cc < 3; cc++)
                    uaccS[tt][quad * 4 + r][cc] = up[r][cc];
            }
        }
        __syncthreads();
        if (tid < 48) {
            int row = tid / 3, cc = tid % 3;
            float s = 0.f;
            #pragma unroll
            for (int t = 0; t < 8; t++) s += uaccS[t][row][cc];
            u[(size_t)(node0 + row) * 3 + cc] = s;
        }
    } else {
        #pragma unroll
        for (int r = 0; r < 4; r++) {
            int row = node0 + quad * 4 + r;
            stnt_f8(&out8[(size_t)row * 128 + col], lrelu(acc[r] + bb));
        }
    }
}

// ---------------- final aggregate (3 ch), unscale, + bias, tanh*0.5 ----------------

__global__ void k_agg_out(const float* __restrict__ u, const int* __restrict__ row_ptr,
                          const int2* __restrict__ csr, const float* __restrict__ dinv,
                          const float* __restrict__ bout, float* __restrict__ out) {
    int node = blockIdx.x * 256 + threadIdx.x;
    if (node >= NN) return;
    float di = dinv[node], w0 = di * di;
    float s0 = u[(size_t)node * 3 + 0] * w0;
    float s1 = u[(size_t)node * 3 + 1] * w0;
    float s2 = u[(size_t)node * 3 + 2] * w0;
    float b0a = 0.f, b1a = 0.f, b2a = 0.f;
    int e = row_ptr[node];
    int e1 = row_ptr[node + 1];
    for (; e + 2 <= e1; e += 2) {
        int2 swa = csr[e], swb = csr[e + 1];
        float wa = __int_as_float(swa.y), wb = __int_as_float(swb.y);
        const float* ua = &u[(size_t)swa.x * 3];
        const float* ub = &u[(size_t)swb.x * 3];
        s0 = fmaf(ua[0], wa, s0);
        s1 = fmaf(ua[1], wa, s1);
        s2 = fmaf(ua[2], wa, s2);
        b0a = fmaf(ub[0], wb, b0a);
        b1a = fmaf(ub[1], wb, b1a);
        b2a = fmaf(ub[2], wb, b2a);
    }
    for (; e < e1; ++e) {
        int2 sw = csr[e];
        float w = __int_as_float(sw.y);
        const float* us = &u[(size_t)sw.x * 3];
        s0 = fmaf(us[0], w, s0);
        s1 = fmaf(us[1], w, s1);
        s2 = fmaf(us[2], w, s2);
    }
    out[(size_t)node * 3 + 0] = tanhf((s0 + b0a) * INVSCALE + bout[0]) * 0.5f;
    out[(size_t)node * 3 + 1] = tanhf((s1 + b1a) * INVSCALE + bout[1]) * 0.5f;
    out[(size_t)node * 3 + 2] = tanhf((s2 + b2a) * INVSCALE + bout[2]) * 0.5f;
}

// ---------------- launch: 11 dispatches ----------------

extern "C" void kernel_launch(void* const* d_in, const int* in_sizes, int n_in,
                              void* d_out, int out_size, void* d_ws, size_t ws_size,
                              hipStream_t stream) {
    const float* x        = (const float*)d_in[0];
    const int*   ei       = (const int*)d_in[1];   // int32: [2, NE] row-major
    const float* W0       = (const float*)d_in[2];
    const float* b0       = (const float*)d_in[3];
    const float* Wh       = (const float*)d_in[4];
    const float* bh       = (const float*)d_in[5];
    const float* Wout     = (const float*)d_in[6];
    const float* bout     = (const float*)d_in[7];
    float* out            = (float*)d_out;

    char* ws = (char*)d_ws;
    float*  bufA   = (float*)(ws + 0);                       // u (NN x 3 fp32)
    unsigned char* bufB8 = (unsigned char*)(ws + 15360000);  // NN*128 fp8
    unsigned char* bufC8 = (unsigned char*)(ws + 23040000);  // NN*128 fp8
    __half* x16    = (__half*)(ws + 30720000);               // NN*64 fp16
    __half* W0t16  = (__half*)(ws + 34560000);               // 128*64 fp16
    __half* Wht16  = (__half*)(ws + 34576384);               // 6*128*128 fp16
    float*  bs     = (float*)(ws + 34772992);                // 7*128 fp32 scaled biases
    float*  dinv   = (float*)(ws + 34776576);                // NN floats
    int*    cnt    = (int*)  (ws + 34896576);                // NN ints
    int*    row_ptr= (int*)  (ws + 35016576);                // NN+1 ints (padded)
    int*    cursor = (int*)  (ws + 35136640);                // NN ints
    int2*   csr    = (int2*) (ws + 35256640);                // NE int2

    hipMemsetAsync(cnt, 0, NN * sizeof(int), stream);
    k_count<<<(NE + 255) / 256, 256, 0, stream>>>(ei, cnt, W0, Wh, b0, bh, x,
                                                  W0t16, Wht16, bs, x16);
    k_scan<<<1, 1024, 0, stream>>>(cnt, row_ptr, cursor, dinv);
    k_fill<<<(NE + 255) / 256, 256, 0, stream>>>(ei, dinv, cursor, csr);

    // layer 0 (fused agg+MFMA, fp16 x): h1' = fp8(lrelu((A_hat x) @ (64*W0) + 64*b0))
    k_layer0<<<NTILE, 512, 0, stream>>>(x16, row_ptr, csr, dinv, W0t16, bs, bufB8);

    // hidden layers 1..5 (fused agg+MFMA, fp8 h), ping-pong; layer 6 additionally
    // fuses the out-GEMM (u = h7' @ Wout) and skips the h7' global store.
    unsigned char* hin = bufB8;
    unsigned char* hout = bufC8;
    for (int i = 0; i < 5; i++) {
        k_layer_h<false><<<NTILE, 512, 0, stream>>>(hin, row_ptr, csr, dinv,
                                                    Wht16 + (size_t)i * 16384,
                                                    bs + 128 + (size_t)i * 128, hout,
                                                    Wout, bufA);
        unsigned char* t = hin; hin = hout; hout = t;
    }
    k_layer_h<true><<<NTILE, 512, 0, stream>>>(hin, row_ptr, csr, dinv,
                                               Wht16 + (size_t)5 * 16384,
                                               bs + 128 + (size_t)5 * 128, hout,
                                               Wout, bufA /* u' : NN x 3 */);

    // final: out = tanh((A_hat u') / 4096 + bout) * 0.5
    k_agg_out<<<(NN + 255) / 256, 256, 0, stream>>>(bufA, row_ptr, csr, dinv, bout, out);
}